// Round 1
// baseline (261.695 us; speedup 1.0000x reference)
//
#include <hip/hip_runtime.h>
#include <hip/hip_bf16.h>
#include <stdint.h>

// GroupCommunication: B=16,S=4096,D=1024; 16 blocks x 64ch; 2 heads x 32 dim.
// Fully fused: grouped QKV (MFMA) -> cross-block attention (MFMA+shfl softmax)
// -> grouped output linear (MFMA). Weights pre-packed to bf16 fragment stream.

typedef __attribute__((ext_vector_type(8))) short bf16x8;
typedef __attribute__((ext_vector_type(4))) float f32x4;

#define NTOK   65536
#define DM     1024
#define NB     16
#define TT     16          // tokens per workgroup
#define QSCALE 0.17677669529663687f   // 32^-0.5
#define LOG2E  1.4426950408889634f

static __device__ __forceinline__ unsigned short f2bf(float f) {
  unsigned int u = __float_as_uint(f);
  u += 0x7fffu + ((u >> 16) & 1u);        // RNE to bf16
  return (unsigned short)(u >> 16);
}

static __device__ __forceinline__ bf16x8 pack8(float4 a, float4 b) {
  bf16x8 r;
  r[0] = (short)f2bf(a.x); r[1] = (short)f2bf(a.y);
  r[2] = (short)f2bf(a.z); r[3] = (short)f2bf(a.w);
  r[4] = (short)f2bf(b.x); r[5] = (short)f2bf(b.y);
  r[6] = (short)f2bf(b.z); r[7] = (short)f2bf(b.w);
  return r;
}

union FragCast { uint4 u4; bf16x8 v; uint2 u2[2]; unsigned int u[4]; };

// ---------------------------------------------------------------------------
// Prologue: pack wq(scaled),wk,wv,wf fp32 [g][i][o] -> bf16 B-fragment stream.
// Layout: [mat(4)][g(16)][kk(2)][nf(4)][lane(64)] x 8 bf16 (one uint4/lane).
// Fragment element j holds W[k = kk*32 + 8*(lane>>4) + j][o = nf*16 + (lane&15)]
// -- identical (lane,elem)->k map as the A-fragments, so any true HW k-perm
// cancels between A and B.
// ---------------------------------------------------------------------------
__global__ void build_wfrag(const float* __restrict__ wq, const float* __restrict__ wk,
                            const float* __restrict__ wv, const float* __restrict__ wf,
                            uint4* __restrict__ wfrag) {
  int tid = blockIdx.x * 256 + threadIdx.x;
  if (tid >= 4 * 16 * 2 * 4 * 64) return;
  int lane =  tid        & 63;
  int nf   = (tid >> 6)  & 3;
  int kk   = (tid >> 8)  & 1;
  int g    = (tid >> 9)  & 15;
  int mat  =  tid >> 13;
  const float* w = (mat == 0) ? wq : (mat == 1) ? wk : (mat == 2) ? wv : wf;
  float sc = (mat == 0) ? QSCALE : 1.0f;
  int o  = nf * 16 + (lane & 15);
  int kb = kk * 32 + 8 * (lane >> 4);
  unsigned int packed[4];
#pragma unroll
  for (int jj = 0; jj < 4; ++jj) {
    unsigned short lo = f2bf(w[(g * 64 + kb + 2 * jj    ) * 64 + o] * sc);
    unsigned short hi = f2bf(w[(g * 64 + kb + 2 * jj + 1) * 64 + o] * sc);
    packed[jj] = (unsigned int)lo | ((unsigned int)hi << 16);
  }
  uint4 u; u.x = packed[0]; u.y = packed[1]; u.z = packed[2]; u.w = packed[3];
  wfrag[tid] = u;
}

// ---------------------------------------------------------------------------
// Fused kernel: 512 threads (8 waves), 16 tokens per workgroup.
// ---------------------------------------------------------------------------
__global__ __launch_bounds__(512, 2)
void fused_gc(const float* __restrict__ x,
              const float* __restrict__ bq, const float* __restrict__ bk,
              const float* __restrict__ bv, const float* __restrict__ bfb,
              const uint4* __restrict__ wfrag,
              float* __restrict__ out) {
  // q,k natural [t][g][h*32+d] (72-elem rows: stride 36 dw -> <=2-way banks, 16B aligned)
  __shared__ __align__(16) unsigned short s_q  [TT][NB][72];
  __shared__ __align__(16) unsigned short s_k  [TT][NB][72];
  // v transposed per (t,h): [d][f] rows of 20 (40B stride: conflict-free, 8B aligned)
  __shared__ __align__(16) unsigned short s_vT [TT][2][32][20];
  // attention result, g-major for the final GEMM's A-fragments
  __shared__ __align__(16) unsigned short s_att[NB][TT][72];
  // per-wave P tile (16x16, rows padded to 20)
  __shared__ __align__(16) unsigned short s_p  [8][16][20];

  const int tid  = threadIdx.x;
  const int wave = tid >> 6;
  const int lane = tid & 63;
  const int lr   = lane & 15;      // row/col within 16-tile
  const int lq   = lane >> 4;      // lane quad
  const long tok0 = (long)blockIdx.x * TT;

  // ---------------- Phase 1: grouped QKV projections ----------------
  const float* xrow = x + (tok0 + lr) * DM;   // lane lr owns token row lr
  float4 xv[2][2][2];
#pragma unroll
  for (int gi = 0; gi < 2; ++gi) {
    int g = wave * 2 + gi;
#pragma unroll
    for (int kk = 0; kk < 2; ++kk) {
      const float* p = xrow + g * 64 + kk * 32 + 8 * lq;
      xv[gi][kk][0] = *(const float4*)(p);
      xv[gi][kk][1] = *(const float4*)(p + 4);
    }
  }
#pragma unroll
  for (int gi = 0; gi < 2; ++gi) {
    int g = wave * 2 + gi;
    bf16x8 afr[2];
    afr[0] = pack8(xv[gi][0][0], xv[gi][0][1]);
    afr[1] = pack8(xv[gi][1][0], xv[gi][1][1]);
#pragma unroll
    for (int mat = 0; mat < 3; ++mat) {
      const float* bp = (mat == 0) ? bq : (mat == 1) ? bk : bv;
      float bsc = (mat == 0) ? QSCALE : 1.0f;
#pragma unroll
      for (int nf = 0; nf < 4; ++nf) {
        int o = nf * 16 + lr;
        float bias = bp[g * 64 + o] * bsc;
        f32x4 acc = {bias, bias, bias, bias};
#pragma unroll
        for (int kk = 0; kk < 2; ++kk) {
          FragCast fc; fc.u4 = wfrag[(((mat * 16 + g) * 2 + kk) * 4 + nf) * 64 + lane];
          acc = __builtin_amdgcn_mfma_f32_16x16x32_bf16(afr[kk], fc.v, acc, 0, 0, 0);
        }
        // D layout (verified): col o = lane&15, row t = 4*(lane>>4)+r
        if (mat == 0) {
#pragma unroll
          for (int r = 0; r < 4; ++r) s_q[4 * lq + r][g][o] = f2bf(acc[r]);
        } else if (mat == 1) {
#pragma unroll
          for (int r = 0; r < 4; ++r) s_k[4 * lq + r][g][o] = f2bf(acc[r]);
        } else {
          int h = o >> 5, d = o & 31;
#pragma unroll
          for (int r = 0; r < 4; ++r) s_vT[4 * lq + r][h][d][g] = f2bf(acc[r]);
        }
      }
    }
  }
  __syncthreads();

  // ---------------- Phase 2: cross-block attention ----------------
#pragma unroll
  for (int j = 0; j < 4; ++j) {
    int t = wave * 2 + (j >> 1);
    int h = j & 1;
    f32x4 zero = {0.f, 0.f, 0.f, 0.f};
    // scores[g][f] = sum_d q[g,d]*k[f,d]: A=Q rows g, B=K^T cols f (= K rows)
    bf16x8 qa = *(const bf16x8*)&s_q[t][lr][h * 32 + 8 * lq];
    bf16x8 ka = *(const bf16x8*)&s_k[t][lr][h * 32 + 8 * lq];
    f32x4 sc4 = __builtin_amdgcn_mfma_f32_16x16x32_bf16(qa, ka, zero, 0, 0, 0);
    // softmax over f: row g = 4*lq+r lives across the 16 lanes (f = lane&15)
#pragma unroll
    for (int r = 0; r < 4; ++r) {
      float m = sc4[r];
      m = fmaxf(m, __shfl_xor(m, 1));
      m = fmaxf(m, __shfl_xor(m, 2));
      m = fmaxf(m, __shfl_xor(m, 4));
      m = fmaxf(m, __shfl_xor(m, 8));
      float p = exp2f((sc4[r] - m) * LOG2E);
      float s = p;
      s += __shfl_xor(s, 1);
      s += __shfl_xor(s, 2);
      s += __shfl_xor(s, 4);
      s += __shfl_xor(s, 8);
      s_p[wave][4 * lq + r][lr] = f2bf(__fdividef(p, s));
    }
    // PV: out[g][d] = sum_f P[g][f] * V[f][d]; K=32 with k>=16 zeroed in regs
    FragCast pa;
    pa.u2[0] = *(const uint2*)&s_p[wave][lr][4 * lq];
    pa.u[2] = 0; pa.u[3] = 0;
#pragma unroll
    for (int nf = 0; nf < 2; ++nf) {
      int d = nf * 16 + lr;
      FragCast vb;
      vb.u2[0] = *(const uint2*)&s_vT[t][h][d][4 * lq];
      vb.u[2] = 0; vb.u[3] = 0;
      f32x4 o4 = __builtin_amdgcn_mfma_f32_16x16x32_bf16(pa.v, vb.v, zero, 0, 0, 0);
#pragma unroll
      for (int r = 0; r < 4; ++r) s_att[4 * lq + r][t][h * 32 + d] = f2bf(o4[r]);
    }
  }
  __syncthreads();

  // ---------------- Phase 3: grouped output linear ----------------
#pragma unroll
  for (int gi = 0; gi < 2; ++gi) {
    int g = wave * 2 + gi;
    bf16x8 aa[2];
    aa[0] = *(const bf16x8*)&s_att[g][lr][     8 * lq];
    aa[1] = *(const bf16x8*)&s_att[g][lr][32 + 8 * lq];
#pragma unroll
    for (int nf = 0; nf < 4; ++nf) {
      int o = nf * 16 + lr;
      float bias = bfb[g * 64 + o];
      f32x4 acc = {bias, bias, bias, bias};
#pragma unroll
      for (int kk = 0; kk < 2; ++kk) {
        FragCast fc; fc.u4 = wfrag[(((3 * 16 + g) * 2 + kk) * 4 + nf) * 64 + lane];
        acc = __builtin_amdgcn_mfma_f32_16x16x32_bf16(aa[kk], fc.v, acc, 0, 0, 0);
      }
#pragma unroll
      for (int r = 0; r < 4; ++r) {
        out[(tok0 + 4 * lq + r) * DM + g * 64 + o] = acc[r];
      }
    }
  }
}

// ---------------------------------------------------------------------------
extern "C" void kernel_launch(void* const* d_in, const int* in_sizes, int n_in,
                              void* d_out, int out_size, void* d_ws, size_t ws_size,
                              hipStream_t stream) {
  const float* x   = (const float*)d_in[0];
  const float* wq  = (const float*)d_in[1];
  const float* bq_ = (const float*)d_in[2];
  const float* wk  = (const float*)d_in[3];
  const float* bk_ = (const float*)d_in[4];
  const float* wv  = (const float*)d_in[5];
  const float* bv_ = (const float*)d_in[6];
  const float* wf  = (const float*)d_in[7];
  const float* bf_ = (const float*)d_in[8];
  (void)in_sizes; (void)n_in; (void)out_size; (void)ws_size;

  uint4* wfrag = (uint4*)d_ws;   // 4*16*2*4*64 frags * 16B = 512 KiB

  build_wfrag<<<128, 256, 0, stream>>>(wq, wk, wv, wf, wfrag);
  fused_gc<<<NTOK / TT, 512, 0, stream>>>(x, bq_, bk_, bv_, bf_, wfrag,
                                          (float*)d_out);
}

// Round 2
// 244.435 us; speedup vs baseline: 1.0706x; 1.0706x over previous
//
#include <hip/hip_runtime.h>
#include <hip/hip_bf16.h>
#include <stdint.h>

// GroupCommunication: 65536 tokens x 1024 ch; 16 blocks x 64ch; 2 heads x 32d.
// Fully fused single pass. 1024-thread WGs (16 waves): wave=g for the grouped
// GEMMs, wave=t for attention. All MFMAs operand-swapped so the D-tile has
// channels on rows (packed b64 LDS writes / float4 stores) and tokens on cols.
// Swapped QK^T makes softmax lane-local; P feeds PV straight from registers.

typedef __attribute__((ext_vector_type(8))) short bf16x8;
typedef __attribute__((ext_vector_type(4))) float f32x4;

#define NTOK   65536
#define DM     1024
#define TT     16
#define QSCALE 0.17677669529663687f   // 32^-0.5
#define LOG2E  1.4426950408889634f

static __device__ __forceinline__ unsigned short f2bf(float f) {
  unsigned int u = __float_as_uint(f);
  u += 0x7fffu + ((u >> 16) & 1u);        // RNE to bf16
  return (unsigned short)(u >> 16);
}

static __device__ __forceinline__ bf16x8 pack8(float4 a, float4 b) {
  bf16x8 r;
  r[0] = (short)f2bf(a.x); r[1] = (short)f2bf(a.y);
  r[2] = (short)f2bf(a.z); r[3] = (short)f2bf(a.w);
  r[4] = (short)f2bf(b.x); r[5] = (short)f2bf(b.y);
  r[6] = (short)f2bf(b.z); r[7] = (short)f2bf(b.w);
  return r;
}

union FragCast { uint4 u4; bf16x8 v; uint2 u2[2]; unsigned int u[4]; };

// ---------------------------------------------------------------------------
// Prologue: pack wq(scaled),wk,wv,wf fp32 [g][i][o] -> bf16 fragment stream.
// Element j of frag holds W[k = kk*32 + 8*(lane>>4) + j][o = nf*16 + (lane&15)].
// Used as the A-operand (rows o, k-slots j) or B-operand symmetrically; both
// sides always share the same (lane,j)->k map, so any HW k-permutation cancels.
// ---------------------------------------------------------------------------
__global__ void build_wfrag(const float* __restrict__ wq, const float* __restrict__ wk,
                            const float* __restrict__ wv, const float* __restrict__ wf,
                            uint4* __restrict__ wfrag) {
  int tid = blockIdx.x * 256 + threadIdx.x;
  if (tid >= 4 * 16 * 2 * 4 * 64) return;
  int lane =  tid        & 63;
  int nf   = (tid >> 6)  & 3;
  int kk   = (tid >> 8)  & 1;
  int g    = (tid >> 9)  & 15;
  int mat  =  tid >> 13;
  const float* w = (mat == 0) ? wq : (mat == 1) ? wk : (mat == 2) ? wv : wf;
  float sc = (mat == 0) ? QSCALE : 1.0f;
  int o  = nf * 16 + (lane & 15);
  int kb = kk * 32 + 8 * (lane >> 4);
  unsigned int packed[4];
#pragma unroll
  for (int jj = 0; jj < 4; ++jj) {
    unsigned short lo = f2bf(w[(g * 64 + kb + 2 * jj    ) * 64 + o] * sc);
    unsigned short hi = f2bf(w[(g * 64 + kb + 2 * jj + 1) * 64 + o] * sc);
    packed[jj] = (unsigned int)lo | ((unsigned int)hi << 16);
  }
  uint4 u; u.x = packed[0]; u.y = packed[1]; u.z = packed[2]; u.w = packed[3];
  wfrag[tid] = u;
}

// ---------------------------------------------------------------------------
// Fused kernel: 1024 threads (16 waves), 16 tokens per workgroup.
// ---------------------------------------------------------------------------
__global__ __launch_bounds__(1024, 4)
void fused_gc(const float* __restrict__ x,
              const float* __restrict__ bq, const float* __restrict__ bk,
              const float* __restrict__ bv, const float* __restrict__ bfb,
              const uint4* __restrict__ wfrag,
              float* __restrict__ out) {
  // q,k: [t][g][64ch] bf16, 16B-block XOR-swizzled by ((t+g)&7) -> 32KB each
  __shared__ __align__(16) unsigned short s_q  [16 * 16 * 64];
  __shared__ __align__(16) unsigned short s_k  [16 * 16 * 64];
  // att: [g][t][64ch], same swizzle by ((g+t)&7) -> 32KB
  __shared__ __align__(16) unsigned short s_att[16 * 16 * 64];
  // v transposed: [t][h][d(32) stride 20][f(16)+pad], +8 shorts t-pad -> 644 dw
  __shared__ __align__(16) unsigned short s_vT [16 * 1288];

  const int tid  = threadIdx.x;
  const int wave = tid >> 6;       // = g (phases 1,3), = t (phase 2)
  const int lane = tid & 63;
  const int lr   = lane & 15;
  const int lq   = lane >> 4;
  const long tok0 = (long)blockIdx.x * TT;
  const int g = wave;

  // ---------------- Phase 1: grouped QKV projections (wave = g) ----------------
  const float* xrow = x + (tok0 + lr) * DM + g * 64;   // lane's token row = lr
  bf16x8 afr[2];
#pragma unroll
  for (int kk = 0; kk < 2; ++kk) {
    const float* p = xrow + kk * 32 + 8 * lq;
    afr[kk] = pack8(*(const float4*)p, *(const float4*)(p + 4));
  }

  // q, k: swapped orientation -> D[o][t], col t = lr, rows o = nf*16+4lq+r
#pragma unroll
  for (int mat = 0; mat < 2; ++mat) {
    const float* bp = mat ? bk : bq;
    const float bsc = mat ? 1.0f : QSCALE;
    unsigned short* dst = mat ? s_k : s_q;
#pragma unroll
    for (int nf = 0; nf < 4; ++nf) {
      float4 b4 = *(const float4*)&bp[g * 64 + nf * 16 + 4 * lq];
      f32x4 acc = {b4.x * bsc, b4.y * bsc, b4.z * bsc, b4.w * bsc};
#pragma unroll
      for (int kk = 0; kk < 2; ++kk) {
        FragCast fc; fc.u4 = wfrag[(((mat * 16 + g) * 2 + kk) * 4 + nf) * 64 + lane];
        acc = __builtin_amdgcn_mfma_f32_16x16x32_bf16(fc.v, afr[kk], acc, 0, 0, 0);
      }
      uint2 wv;
      wv.x = (unsigned int)f2bf(acc[0]) | ((unsigned int)f2bf(acc[1]) << 16);
      wv.y = (unsigned int)f2bf(acc[2]) | ((unsigned int)f2bf(acc[3]) << 16);
      int blk = nf * 2 + (lq >> 1);                       // o>>3
      int idx = ((lr * 16 + g) * 8 + (blk ^ ((lr + g) & 7))) * 8 + 4 * (lq & 1);
      *(uint2*)&dst[idx] = wv;                            // q/k[t=lr][g][o..o+3]
    }
  }
  // v: original orientation -> D[t][o], col o = nf*16+lr, rows t = 4lq+r
#pragma unroll
  for (int nf = 0; nf < 4; ++nf) {
    int o = nf * 16 + lr;
    float bias = bv[g * 64 + o];
    f32x4 acc = {bias, bias, bias, bias};
#pragma unroll
    for (int kk = 0; kk < 2; ++kk) {
      FragCast fc; fc.u4 = wfrag[(((2 * 16 + g) * 2 + kk) * 4 + nf) * 64 + lane];
      acc = __builtin_amdgcn_mfma_f32_16x16x32_bf16(afr[kk], fc.v, acc, 0, 0, 0);
    }
    int h = nf >> 1, d = (nf & 1) * 16 + lr;
#pragma unroll
    for (int r = 0; r < 4; ++r) {
      s_vT[(4 * lq + r) * 1288 + h * 640 + d * 20 + g] = f2bf(acc[r]); // V[f=g][d] at [t][h][d][f]
    }
  }
  __syncthreads();

  // ---------------- Phase 2: cross-block attention (wave = t) ----------------
  const int t = wave;
#pragma unroll
  for (int h = 0; h < 2; ++h) {
    f32x4 zero = {0.f, 0.f, 0.f, 0.f};
    FragCast qa, ka;
    int rblk = ((h * 4 + lq) ^ ((t + lr) & 7)) * 8;
    qa.u4 = *(const uint4*)&s_q[(t * 16 + lr) * 64 + rblk];
    ka.u4 = *(const uint4*)&s_k[(t * 16 + lr) * 64 + rblk];
    // D[f][g]: col g = lr, rows f = 4lq+r  (score[g][f] transposed)
    f32x4 sc4 = __builtin_amdgcn_mfma_f32_16x16x32_bf16(ka.v, qa.v, zero, 0, 0, 0);
    // softmax over f: in-lane over 4 regs, then across the 4 lq lanes
    float m = fmaxf(fmaxf(sc4[0], sc4[1]), fmaxf(sc4[2], sc4[3]));
    m = fmaxf(m, __shfl_xor(m, 16));
    m = fmaxf(m, __shfl_xor(m, 32));
    float p0 = exp2f((sc4[0] - m) * LOG2E);
    float p1 = exp2f((sc4[1] - m) * LOG2E);
    float p2 = exp2f((sc4[2] - m) * LOG2E);
    float p3 = exp2f((sc4[3] - m) * LOG2E);
    float s = p0 + p1 + p2 + p3;
    s += __shfl_xor(s, 16);
    s += __shfl_xor(s, 32);
    float inv = __fdividef(1.0f, s);
    FragCast pa;      // P[g=lr][f=4lq+j] lives in this very lane -- no LDS
    pa.u[0] = (unsigned int)f2bf(p0 * inv) | ((unsigned int)f2bf(p1 * inv) << 16);
    pa.u[1] = (unsigned int)f2bf(p2 * inv) | ((unsigned int)f2bf(p3 * inv) << 16);
    pa.u[2] = 0; pa.u[3] = 0;
#pragma unroll
    for (int nf = 0; nf < 2; ++nf) {
      FragCast va;    // A = V^T: rows d = nf*16+lr, slots j -> f = 4lq+j
      va.u2[0] = *(const uint2*)&s_vT[t * 1288 + h * 640 + (nf * 16 + lr) * 20 + 4 * lq];
      va.u[2] = 0; va.u[3] = 0;
      // D[d][g]: col g = lr, rows d = nf*16+4lq+r
      f32x4 o4 = __builtin_amdgcn_mfma_f32_16x16x32_bf16(va.v, pa.v, zero, 0, 0, 0);
      uint2 wv;
      wv.x = (unsigned int)f2bf(o4[0]) | ((unsigned int)f2bf(o4[1]) << 16);
      wv.y = (unsigned int)f2bf(o4[2]) | ((unsigned int)f2bf(o4[3]) << 16);
      int blk = h * 4 + nf * 2 + (lq >> 1);               // o>>3, o = h*32+nf*16+4lq
      int idx = ((lr * 16 + t) * 8 + (blk ^ ((lr + t) & 7))) * 8 + 4 * (lq & 1);
      *(uint2*)&s_att[idx] = wv;                          // att[g=lr][t][o..o+3]
    }
  }
  __syncthreads();

  // ---------------- Phase 3: grouped output linear (wave = g) ----------------
  FragCast aa[2];
#pragma unroll
  for (int kk = 0; kk < 2; ++kk) {
    int rblk = ((kk * 4 + lq) ^ ((g + lr) & 7)) * 8;
    aa[kk].u4 = *(const uint4*)&s_att[(g * 16 + lr) * 64 + rblk];  // att[g][t=lr][c]
  }
#pragma unroll
  for (int nf = 0; nf < 4; ++nf) {
    float4 b4 = *(const float4*)&bfb[g * 64 + nf * 16 + 4 * lq];
    f32x4 acc = {b4.x, b4.y, b4.z, b4.w};
#pragma unroll
    for (int kk = 0; kk < 2; ++kk) {
      FragCast fc; fc.u4 = wfrag[(((3 * 16 + g) * 2 + kk) * 4 + nf) * 64 + lane];
      acc = __builtin_amdgcn_mfma_f32_16x16x32_bf16(fc.v, aa[kk].v, acc, 0, 0, 0);
    }
    // D[o][t]: col t = lr, rows o = nf*16+4lq+r -> one float4 store
    float4 o4; o4.x = acc[0]; o4.y = acc[1]; o4.z = acc[2]; o4.w = acc[3];
    *(float4*)&out[(tok0 + lr) * DM + g * 64 + nf * 16 + 4 * lq] = o4;
  }
}

// ---------------------------------------------------------------------------
extern "C" void kernel_launch(void* const* d_in, const int* in_sizes, int n_in,
                              void* d_out, int out_size, void* d_ws, size_t ws_size,
                              hipStream_t stream) {
  const float* x   = (const float*)d_in[0];
  const float* wq  = (const float*)d_in[1];
  const float* bq_ = (const float*)d_in[2];
  const float* wk  = (const float*)d_in[3];
  const float* bk_ = (const float*)d_in[4];
  const float* wv  = (const float*)d_in[5];
  const float* bv_ = (const float*)d_in[6];
  const float* wf  = (const float*)d_in[7];
  const float* bf_ = (const float*)d_in[8];
  (void)in_sizes; (void)n_in; (void)out_size; (void)ws_size;

  uint4* wfrag = (uint4*)d_ws;   // 4*16*2*4*64 frags * 16B = 512 KiB

  build_wfrag<<<128, 256, 0, stream>>>(wq, wk, wv, wf, wfrag);
  fused_gc<<<NTOK / TT, 1024, 0, stream>>>(x, bq_, bk_, bv_, bf_, wfrag,
                                           (float*)d_out);
}